// Round 17
// baseline (149.566 us; speedup 1.0000x reference)
//
#include <hip/hip_runtime.h>

#define N_NODES  100000
#define N_EDGES  1250000
#define F_IN     128
#define F_OUT    64
#define N_GRAPHS 256
#define NB_LIN   1563          // total 64-node linear tiles
#define NB_LINB  391           // MFMA blocks; 4 tiles each, W staged once
#define NBKT     782           // coarse buckets: col>>7 (128 nodes each)
#define NCHK     256           // edge chunks
#define CHKSZ    4883          // ceil(E/NCHK); 256*4883 = 1250048
#define M_H      (NBKT * NCHK) // 200192 histogram cells
#define MB_H     196           // ceil(M_H/1024)
#define BKT_CAP  2048          // max edges per bucket (mean 1600, 11 sigma)

typedef __attribute__((ext_vector_type(8))) short short8;   // 8 bf16 (4 VGPRs)
typedef __attribute__((ext_vector_type(4))) float f32x4;

static __device__ __forceinline__ unsigned short f2bf(float f) {
    unsigned u = __builtin_bit_cast(unsigned, f);
    u += 0x7fff + ((u >> 16) & 1);            // RNE
    return (unsigned short)(u >> 16);
}
static __device__ __forceinline__ float bf2f(unsigned short h) {
    unsigned u = ((unsigned)h) << 16;
    return __builtin_bit_cast(float, u);
}
static __device__ __forceinline__ float bflo(unsigned v) {   // low bf16 of packed u32
    return __builtin_bit_cast(float, v << 16);
}
static __device__ __forceinline__ float bfhi(unsigned v) {   // high bf16 of packed u32
    return __builtin_bit_cast(float, v & 0xffff0000u);
}

// ---------------- chunk histograms (LDS counters, no global atomics) ----------------
__global__ __launch_bounds__(256) void hist_k(const int* __restrict__ col,
                                              int* __restrict__ H) {
    __shared__ int cnt[NBKT];
    int c = blockIdx.x, tid = threadIdx.x;
    for (int b = tid; b < NBKT; b += 256) cnt[b] = 0;
    __syncthreads();
    int s = c * CHKSZ;
    int e = s + CHKSZ; if (e > N_EDGES) e = N_EDGES;
    for (int i = s + tid; i < e; i += 256)
        atomicAdd(&cnt[col[i] >> 7], 1);       // LDS atomic: ~1 lane-op/edge
    __syncthreads();
    for (int b = tid; b < NBKT; b += 256)
        H[b * NCHK + c] = cnt[b];
}

// ---------------- exclusive scan of H (lexicographic (bucket, chunk)) ----------
__global__ __launch_bounds__(1024) void scanH1_k(int* __restrict__ H, int* __restrict__ bsum) {
    __shared__ int lds[1024];
    int tid = threadIdx.x;
    int i = blockIdx.x * 1024 + tid;
    int v = (i < M_H) ? H[i] : 0;
    lds[tid] = v;
    __syncthreads();
    for (int off = 1; off < 1024; off <<= 1) {
        int t = (tid >= off) ? lds[tid - off] : 0;
        __syncthreads();
        lds[tid] += t;
        __syncthreads();
    }
    if (i < M_H) H[i] = lds[tid] - v;
    if (tid == 1023) bsum[blockIdx.x] = lds[tid];
}

__global__ __launch_bounds__(256) void scanH2_k(int* __restrict__ bsum) {
    __shared__ int lds[256];
    int tid = threadIdx.x;
    int v = (tid < MB_H) ? bsum[tid] : 0;
    lds[tid] = v;
    __syncthreads();
    for (int off = 1; off < 256; off <<= 1) {
        int t = (tid >= off) ? lds[tid - off] : 0;
        __syncthreads();
        lds[tid] += t;
        __syncthreads();
    }
    if (tid < MB_H) bsum[tid] = lds[tid] - v;
}

__global__ __launch_bounds__(1024) void scanH3_k(int* __restrict__ H, const int* __restrict__ bsum) {
    int i = blockIdx.x * 1024 + threadIdx.x;
    if (i < M_H) H[i] += bsum[blockIdx.x];
}

// ---------------- fused: scatter-partition + MFMA linear (overlap) ----------------
__global__ __launch_bounds__(256) void scatter_lin_k(const int* __restrict__ row,
                                                     const int* __restrict__ col,
                                                     const int* __restrict__ Hs,
                                                     int2* __restrict__ part,
                                                     const float* __restrict__ x,
                                                     const float* __restrict__ W,
                                                     unsigned short* __restrict__ z) {
    __shared__ unsigned smem[2 * 64 * 64];     // 32 KB, overlaid per path
    int tid = threadIdx.x;

    if (blockIdx.x < NCHK) {
        int* cur = (int*)smem;                 // NBKT cursors overlay
        int c = blockIdx.x;
        for (int b = tid; b < NBKT; b += 256) cur[b] = Hs[b * NCHK + c];
        __syncthreads();
        int s = c * CHKSZ;
        int e = s + CHKSZ; if (e > N_EDGES) e = N_EDGES;
        for (int i = s + tid; i < e; i += 256) {
            int cc = col[i], rr = row[i];
            int p = atomicAdd(&cur[cc >> 7], 1);      // LDS atomic w/ return
            part[p] = make_int2(rr, cc);
        }
        return;
    }

    // ---- linear section ----
    unsigned* xs = smem;
    unsigned* ws = smem + 64 * 64;
    int lb = blockIdx.x - NCHK;

    #pragma unroll
    for (int rr = 0; rr < 8; ++rr) {
        int idx = rr * 256 + tid;
        int n = idx >> 5, q = idx & 31;
        int d   = (n << 6) + (q << 1);
        int sdw = (n & 7) << 2;
        const float4 wv = *(const float4*)(W + (size_t)n * F_IN + q * 4);
        ws[(d ^ sdw)]     = (unsigned)f2bf(wv.x) | ((unsigned)f2bf(wv.y) << 16);
        ws[(d ^ sdw) + 1] = (unsigned)f2bf(wv.z) | ((unsigned)f2bf(wv.w) << 16);
    }

    int lane = tid & 63;
    int wv_  = tid >> 6;
    int m0   = wv_ << 4;
    int lr   = lane & 15;
    int lg   = lane >> 4;

    for (int t4 = 0; t4 < 4; ++t4) {
        int tile = lb * 4 + t4;
        if (tile >= NB_LIN) break;
        int base = tile * 64;
        int nmax = N_NODES - base; if (nmax > 64) nmax = 64;

        #pragma unroll
        for (int rr = 0; rr < 8; ++rr) {
            int idx = rr * 256 + tid;
            int n = idx >> 5, q = idx & 31;
            int d   = (n << 6) + (q << 1);
            int sdw = (n & 7) << 2;
            float4 xv = make_float4(0.f, 0.f, 0.f, 0.f);
            if (n < nmax) xv = *(const float4*)(x + (size_t)(base + n) * F_IN + q * 4);
            xs[(d ^ sdw)]     = (unsigned)f2bf(xv.x) | ((unsigned)f2bf(xv.y) << 16);
            xs[(d ^ sdw) + 1] = (unsigned)f2bf(xv.z) | ((unsigned)f2bf(xv.w) << 16);
        }
        __syncthreads();

        f32x4 acc0 = (f32x4)(0.f), acc1 = (f32x4)(0.f);
        f32x4 acc2 = (f32x4)(0.f), acc3 = (f32x4)(0.f);

        #pragma unroll
        for (int t = 0; t < 4; ++t) {
            int nn = m0 + lr;
            int da = ((nn << 6) + (t << 4) + (lg << 2)) ^ ((nn & 7) << 2);
            short8 a = *(const short8*)(xs + da);
            #pragma unroll
            for (int ff = 0; ff < 4; ++ff) {
                int f  = (ff << 4) + lr;
                int db = ((f << 6) + (t << 4) + (lg << 2)) ^ ((f & 7) << 2);
                short8 b = *(const short8*)(ws + db);
                f32x4 c = (ff == 0) ? acc0 : (ff == 1) ? acc1 : (ff == 2) ? acc2 : acc3;
                c = __builtin_amdgcn_mfma_f32_16x16x32_bf16(a, b, c, 0, 0, 0);
                if (ff == 0) acc0 = c; else if (ff == 1) acc1 = c;
                else if (ff == 2) acc2 = c; else acc3 = c;
            }
        }

        #pragma unroll
        for (int r = 0; r < 4; ++r) {
            int node = m0 + (lg << 2) + r;
            if (node < nmax) {
                size_t o = (size_t)(base + node) * F_OUT + lr;
                z[o +  0] = f2bf(acc0[r]);
                z[o + 16] = f2bf(acc1[r]);
                z[o + 32] = f2bf(acc2[r]);
                z[o + 48] = f2bf(acc3[r]);
            }
        }
        __syncthreads();
    }
}

// ---------------- per-bucket CSR finalize: deg/offs/dis + place rows + scale z --------
__global__ __launch_bounds__(256) void csr_k(const int* __restrict__ Hs,
                                             const int2* __restrict__ part,
                                             int* __restrict__ bucketF,
                                             int* __restrict__ deg,
                                             int* __restrict__ offs,
                                             float* __restrict__ dis,
                                             unsigned* __restrict__ z32) {
    __shared__ int rowL[BKT_CAP];
    __shared__ int colL[BKT_CAP];
    __shared__ int cnt[128], offsL[128], curL[128], scanT[128];
    __shared__ float disL[128];
    int b = blockIdx.x, tid = threadIdx.x;
    int s = Hs[b * NCHK];
    int e = (b < NBKT - 1) ? Hs[(b + 1) * NCHK] : N_EDGES;
    int m = e - s;

    if (tid < 128) cnt[tid] = 0;
    __syncthreads();
    for (int i = tid; i < m; i += 256) {
        int2 pr = part[s + i];
        rowL[i] = pr.x;
        int cl = pr.y & 127;
        colL[i] = cl;
        atomicAdd(&cnt[cl], 1);
    }
    __syncthreads();
    if (tid < 128) scanT[tid] = cnt[tid];
    __syncthreads();
    for (int off = 1; off < 128; off <<= 1) {
        int v = (tid < 128 && tid >= off) ? scanT[tid - off] : 0;
        __syncthreads();
        if (tid < 128) scanT[tid] += v;
        __syncthreads();
    }
    if (tid < 128) {
        int ex = scanT[tid] - cnt[tid];
        offsL[tid] = ex;
        curL[tid]  = ex;
        float d = rsqrtf((float)cnt[tid] + 1.0f);
        disL[tid] = d;
        int node = b * 128 + tid;
        if (node < N_NODES) {
            deg[node]  = cnt[tid];
            offs[node] = s + ex;
            dis[node]  = d;
        }
    }
    __syncthreads();
    for (int i = tid; i < m; i += 256) {
        int cl = colL[i];
        int p = atomicAdd(&curL[cl], 1);
        bucketF[s + p] = rowL[i];
    }
    // scale z in place: y = dis * z (node = tid>>1, 16 u32 each)
    int node = tid >> 1, half = tid & 1;
    int gnode = b * 128 + node;
    if (gnode < N_NODES) {
        float d = disL[node];
        unsigned* zp = z32 + (size_t)gnode * 32 + half * 16;
        #pragma unroll
        for (int k = 0; k < 16; ++k) {
            unsigned v = zp[k];
            zp[k] = (unsigned)f2bf(d * bflo(v)) | ((unsigned)f2bf(d * bfhi(v)) << 16);
        }
    }
}

// ---------------- gather_v10: v6 structure, 4 nodes/wave (shorter serial chains) -----
// Wave handles 4 consecutive nodes. lane = (eo = lane>>5 edge slot, fp = lane&31
// feature pair u32). 8-deep unroll -> 16 edges in flight. y pre-scaled.
__global__ __launch_bounds__(256, 4) void gather_pool_k(const unsigned short* __restrict__ y,
                                                        const int* __restrict__ offs,
                                                        const int* __restrict__ deg,
                                                        const int* __restrict__ bucket,
                                                        const float* __restrict__ dis,
                                                        const int* __restrict__ batch,
                                                        const float* __restrict__ bias,
                                                        float* __restrict__ psum,
                                                        int* __restrict__ pcnt) {
    int lane = threadIdx.x & 63;
    int wid  = threadIdx.x >> 6;
    int i0   = (blockIdx.x * 4 + wid) * 4;   // 100000 = 6250 * 16, exact
    int eo   = lane >> 5;                    // edge slot 0/1
    int fp   = lane & 31;                    // feature pair: feats 2fp, 2fp+1
    float bx = bias[2 * fp], by = bias[2 * fp + 1];
    const unsigned short* yb = y + 2 * fp;

    // prefetch the 4 nodes' metadata lane-parallel, distribute via shfl
    int   om = (lane < 4) ? offs[i0 + lane]  : 0;
    int   dm = (lane < 4) ? deg[i0 + lane]   : 0;
    float sm = (lane < 4) ? dis[i0 + lane]   : 0.f;
    int   gm = (lane < 4) ? batch[i0 + lane] : 0;

    float rx = 0.f, ry = 0.f;
    int cur = -1, runlen = 0;
    #pragma unroll
    for (int n = 0; n < 4; ++n) {
        int i = i0 + n;
        int s = __shfl(om, n);
        int e = s + __shfl(dm, n);

        // self-loop term (pre-scaled y), counted in slot 0 only
        unsigned sv = *(const unsigned*)(yb + (size_t)i * F_OUT);
        float ax = (eo == 0) ? bflo(sv) : 0.f;
        float ay = (eo == 0) ? bfhi(sv) : 0.f;

        for (int j = s; j < e; j += 16) {
            #pragma unroll
            for (int u = 0; u < 8; ++u) {
                int id  = j + 2 * u + eo;
                int idc = (id < e) ? id : e - 1;          // clamp: load unconditional
                int r   = bucket[idc];
                unsigned w = *(const unsigned*)(yb + (size_t)r * F_OUT);
                float wx = bflo(w), wy = bfhi(w);
                ax += (id < e) ? wx : 0.f;                // per-lane cndmask, no branch
                ay += (id < e) ? wy : 0.f;
            }
        }
        // combine the two edge slots (both halves end with the full sum)
        ax += __shfl_xor(ax, 32);
        ay += __shfl_xor(ay, 32);

        float di = __shfl(sm, n);
        float vx = fmaxf(fmaf(di, ax, bx), 0.f);
        float vy = fmaxf(fmaf(di, ay, by), 0.f);
        int g = __shfl(gm, n);
        if (g != cur) {
            if (cur >= 0 && eo == 0) {
                atomicAdd(&psum[cur * F_OUT + 2 * fp],     rx);
                atomicAdd(&psum[cur * F_OUT + 2 * fp + 1], ry);
                if (lane == 0) atomicAdd(&pcnt[cur], runlen);
            }
            cur = g; rx = 0.f; ry = 0.f; runlen = 0;
        }
        rx += vx; ry += vy; runlen++;
    }
    if (cur >= 0 && eo == 0) {
        atomicAdd(&psum[cur * F_OUT + 2 * fp],     rx);
        atomicAdd(&psum[cur * F_OUT + 2 * fp + 1], ry);
        if (lane == 0) atomicAdd(&pcnt[cur], runlen);
    }
}

// ---------------- out = psum / max(count,1) ----------------
__global__ __launch_bounds__(256) void final_k(const float* __restrict__ psum,
                                               const int* __restrict__ pcnt,
                                               float* __restrict__ out) {
    int t = blockIdx.x * blockDim.x + threadIdx.x;
    if (t < N_GRAPHS * F_OUT) {
        int g = t >> 6;
        float c = (float)(pcnt[g] > 1 ? pcnt[g] : 1);
        out[t] = psum[t] / c;
    }
}

extern "C" void kernel_launch(void* const* d_in, const int* in_sizes, int n_in,
                              void* d_out, int out_size, void* d_ws, size_t ws_size,
                              hipStream_t stream) {
    const float* node_feat = (const float*)d_in[0];
    const int*   edges     = (const int*)d_in[1];   // [2, E] flat: row then col
    const int*   batch     = (const int*)d_in[2];
    const float* W         = (const float*)d_in[3];
    const float* b         = (const float*)d_in[4];

    // workspace carve-up (~30 MB)
    unsigned short* z = (unsigned short*)d_ws;               // N*64 bf16 (scaled in place)
    int2*  part    = (int2*)(z + (size_t)N_NODES * F_OUT);   // E pairs
    int*   bucketF = (int*)(part + N_EDGES);                 // E
    int*   H       = bucketF + N_EDGES;                      // M_H
    int*   bsumH   = H + M_H;                                // 256
    int*   deg     = bsumH + 256;                            // N
    int*   offs    = deg + N_NODES;                          // N
    float* dis     = (float*)(offs + N_NODES);               // N
    float* psum    = dis + N_NODES;                          // G*64
    int*   pcnt    = (int*)(psum + N_GRAPHS * F_OUT);        // G

    hipMemsetAsync(psum, 0, ((size_t)N_GRAPHS * F_OUT + N_GRAPHS) * 4, stream);

    const int* row = edges;
    const int* col = edges + N_EDGES;

    hist_k<<<NCHK, 256, 0, stream>>>(col, H);
    scanH1_k<<<MB_H, 1024, 0, stream>>>(H, bsumH);
    scanH2_k<<<1, 256, 0, stream>>>(bsumH);
    scanH3_k<<<MB_H, 1024, 0, stream>>>(H, bsumH);
    scatter_lin_k<<<NCHK + NB_LINB, 256, 0, stream>>>(row, col, H, part,
                                                      node_feat, W, z);
    csr_k<<<NBKT, 256, 0, stream>>>(H, part, bucketF, deg, offs, dis, (unsigned*)z);
    gather_pool_k<<<N_NODES / 16, 256, 0, stream>>>(z, offs, deg, bucketF,
                                                    dis, batch, b, psum, pcnt);
    final_k<<<(N_GRAPHS * F_OUT + 255) / 256, 256, 0, stream>>>(psum, pcnt, (float*)d_out);
}

// Round 18
// 118.980 us; speedup vs baseline: 1.2571x; 1.2571x over previous
//
#include <hip/hip_runtime.h>

#define N_NODES  100000
#define N_EDGES  1250000
#define F_IN     128
#define F_OUT    64
#define N_GRAPHS 256
#define NB_LIN   1563          // total 64-node linear tiles
#define NB_LINB  391           // MFMA blocks; 4 tiles each, W staged once
#define NBKT     782           // coarse buckets: col>>7 (128 nodes each)
#define NCHK     256           // edge chunks
#define CHKSZ    4883          // ceil(E/NCHK); 256*4883 = 1250048
#define M_H      (NBKT * NCHK) // 200192 histogram cells
#define MB_H     196           // ceil(M_H/1024)
#define BKT_CAP  2048          // max edges per bucket (mean 1600, 11 sigma)

typedef __attribute__((ext_vector_type(8))) short short8;   // 8 bf16 (4 VGPRs)
typedef __attribute__((ext_vector_type(4))) float f32x4;

static __device__ __forceinline__ unsigned short f2bf(float f) {
    unsigned u = __builtin_bit_cast(unsigned, f);
    u += 0x7fff + ((u >> 16) & 1);            // RNE
    return (unsigned short)(u >> 16);
}
static __device__ __forceinline__ float bf2f(unsigned short h) {
    unsigned u = ((unsigned)h) << 16;
    return __builtin_bit_cast(float, u);
}
static __device__ __forceinline__ float bflo(unsigned v) {   // low bf16 of packed u32
    return __builtin_bit_cast(float, v << 16);
}
static __device__ __forceinline__ float bfhi(unsigned v) {   // high bf16 of packed u32
    return __builtin_bit_cast(float, v & 0xffff0000u);
}

// ---------------- chunk histograms (LDS counters, no global atomics) ----------------
__global__ __launch_bounds__(256) void hist_k(const int* __restrict__ col,
                                              int* __restrict__ H) {
    __shared__ int cnt[NBKT];
    int c = blockIdx.x, tid = threadIdx.x;
    for (int b = tid; b < NBKT; b += 256) cnt[b] = 0;
    __syncthreads();
    int s = c * CHKSZ;
    int e = s + CHKSZ; if (e > N_EDGES) e = N_EDGES;
    for (int i = s + tid; i < e; i += 256)
        atomicAdd(&cnt[col[i] >> 7], 1);       // LDS atomic: ~1 lane-op/edge
    __syncthreads();
    for (int b = tid; b < NBKT; b += 256)
        H[b * NCHK + c] = cnt[b];
}

// ---------------- exclusive scan of H (lexicographic (bucket, chunk)) ----------
__global__ __launch_bounds__(1024) void scanH1_k(int* __restrict__ H, int* __restrict__ bsum) {
    __shared__ int lds[1024];
    int tid = threadIdx.x;
    int i = blockIdx.x * 1024 + tid;
    int v = (i < M_H) ? H[i] : 0;
    lds[tid] = v;
    __syncthreads();
    for (int off = 1; off < 1024; off <<= 1) {
        int t = (tid >= off) ? lds[tid - off] : 0;
        __syncthreads();
        lds[tid] += t;
        __syncthreads();
    }
    if (i < M_H) H[i] = lds[tid] - v;
    if (tid == 1023) bsum[blockIdx.x] = lds[tid];
}

__global__ __launch_bounds__(256) void scanH2_k(int* __restrict__ bsum) {
    __shared__ int lds[256];
    int tid = threadIdx.x;
    int v = (tid < MB_H) ? bsum[tid] : 0;
    lds[tid] = v;
    __syncthreads();
    for (int off = 1; off < 256; off <<= 1) {
        int t = (tid >= off) ? lds[tid - off] : 0;
        __syncthreads();
        lds[tid] += t;
        __syncthreads();
    }
    if (tid < MB_H) bsum[tid] = lds[tid] - v;
}

__global__ __launch_bounds__(1024) void scanH3_k(int* __restrict__ H, const int* __restrict__ bsum) {
    int i = blockIdx.x * 1024 + threadIdx.x;
    if (i < M_H) H[i] += bsum[blockIdx.x];
}

// ---------------- fused: scatter-partition + MFMA linear (overlap) ----------------
// part entries packed: row | (col&127)<<17  (row < 2^17, local col 7 bits)
__global__ __launch_bounds__(256) void scatter_lin_k(const int* __restrict__ row,
                                                     const int* __restrict__ col,
                                                     const int* __restrict__ Hs,
                                                     unsigned* __restrict__ part,
                                                     const float* __restrict__ x,
                                                     const float* __restrict__ W,
                                                     unsigned short* __restrict__ z) {
    __shared__ unsigned smem[2 * 64 * 64];     // 32 KB, overlaid per path
    int tid = threadIdx.x;

    if (blockIdx.x < NCHK) {
        int* cur = (int*)smem;                 // NBKT cursors overlay
        int c = blockIdx.x;
        for (int b = tid; b < NBKT; b += 256) cur[b] = Hs[b * NCHK + c];
        __syncthreads();
        int s = c * CHKSZ;
        int e = s + CHKSZ; if (e > N_EDGES) e = N_EDGES;
        for (int i = s + tid; i < e; i += 256) {
            int cc = col[i], rr = row[i];
            int p = atomicAdd(&cur[cc >> 7], 1);      // LDS atomic w/ return
            part[p] = (unsigned)rr | ((unsigned)(cc & 127) << 17);
        }
        return;
    }

    // ---- linear section ----
    unsigned* xs = smem;
    unsigned* ws = smem + 64 * 64;
    int lb = blockIdx.x - NCHK;

    #pragma unroll
    for (int rr = 0; rr < 8; ++rr) {
        int idx = rr * 256 + tid;
        int n = idx >> 5, q = idx & 31;
        int d   = (n << 6) + (q << 1);
        int sdw = (n & 7) << 2;
        const float4 wv = *(const float4*)(W + (size_t)n * F_IN + q * 4);
        ws[(d ^ sdw)]     = (unsigned)f2bf(wv.x) | ((unsigned)f2bf(wv.y) << 16);
        ws[(d ^ sdw) + 1] = (unsigned)f2bf(wv.z) | ((unsigned)f2bf(wv.w) << 16);
    }

    int lane = tid & 63;
    int wv_  = tid >> 6;
    int m0   = wv_ << 4;
    int lr   = lane & 15;
    int lg   = lane >> 4;

    for (int t4 = 0; t4 < 4; ++t4) {
        int tile = lb * 4 + t4;
        if (tile >= NB_LIN) break;
        int base = tile * 64;
        int nmax = N_NODES - base; if (nmax > 64) nmax = 64;

        #pragma unroll
        for (int rr = 0; rr < 8; ++rr) {
            int idx = rr * 256 + tid;
            int n = idx >> 5, q = idx & 31;
            int d   = (n << 6) + (q << 1);
            int sdw = (n & 7) << 2;
            float4 xv = make_float4(0.f, 0.f, 0.f, 0.f);
            if (n < nmax) xv = *(const float4*)(x + (size_t)(base + n) * F_IN + q * 4);
            xs[(d ^ sdw)]     = (unsigned)f2bf(xv.x) | ((unsigned)f2bf(xv.y) << 16);
            xs[(d ^ sdw) + 1] = (unsigned)f2bf(xv.z) | ((unsigned)f2bf(xv.w) << 16);
        }
        __syncthreads();

        f32x4 acc0 = (f32x4)(0.f), acc1 = (f32x4)(0.f);
        f32x4 acc2 = (f32x4)(0.f), acc3 = (f32x4)(0.f);

        #pragma unroll
        for (int t = 0; t < 4; ++t) {
            int nn = m0 + lr;
            int da = ((nn << 6) + (t << 4) + (lg << 2)) ^ ((nn & 7) << 2);
            short8 a = *(const short8*)(xs + da);
            #pragma unroll
            for (int ff = 0; ff < 4; ++ff) {
                int f  = (ff << 4) + lr;
                int db = ((f << 6) + (t << 4) + (lg << 2)) ^ ((f & 7) << 2);
                short8 b = *(const short8*)(ws + db);
                f32x4 c = (ff == 0) ? acc0 : (ff == 1) ? acc1 : (ff == 2) ? acc2 : acc3;
                c = __builtin_amdgcn_mfma_f32_16x16x32_bf16(a, b, c, 0, 0, 0);
                if (ff == 0) acc0 = c; else if (ff == 1) acc1 = c;
                else if (ff == 2) acc2 = c; else acc3 = c;
            }
        }

        #pragma unroll
        for (int r = 0; r < 4; ++r) {
            int node = m0 + (lg << 2) + r;
            if (node < nmax) {
                size_t o = (size_t)(base + node) * F_OUT + lr;
                z[o +  0] = f2bf(acc0[r]);
                z[o + 16] = f2bf(acc1[r]);
                z[o + 32] = f2bf(acc2[r]);
                z[o + 48] = f2bf(acc3[r]);
            }
        }
        __syncthreads();
    }
}

// ---------------- per-bucket CSR finalize: deg/offs/dis + place rows + scale z --------
__global__ __launch_bounds__(256) void csr_k(const int* __restrict__ Hs,
                                             const unsigned* __restrict__ part,
                                             int* __restrict__ bucketF,
                                             int* __restrict__ deg,
                                             int* __restrict__ offs,
                                             float* __restrict__ dis,
                                             unsigned* __restrict__ z32) {
    __shared__ int rowL[BKT_CAP];
    __shared__ int colL[BKT_CAP];
    __shared__ int cnt[128], offsL[128], curL[128], scanT[128];
    __shared__ float disL[128];
    int b = blockIdx.x, tid = threadIdx.x;
    int s = Hs[b * NCHK];
    int e = (b < NBKT - 1) ? Hs[(b + 1) * NCHK] : N_EDGES;
    int m = e - s;

    if (tid < 128) cnt[tid] = 0;
    __syncthreads();
    for (int i = tid; i < m; i += 256) {
        unsigned pr = part[s + i];
        rowL[i] = (int)(pr & 0x1FFFFu);
        int cl = (int)(pr >> 17);
        colL[i] = cl;
        atomicAdd(&cnt[cl], 1);
    }
    __syncthreads();
    if (tid < 128) scanT[tid] = cnt[tid];
    __syncthreads();
    for (int off = 1; off < 128; off <<= 1) {
        int v = (tid < 128 && tid >= off) ? scanT[tid - off] : 0;
        __syncthreads();
        if (tid < 128) scanT[tid] += v;
        __syncthreads();
    }
    if (tid < 128) {
        int ex = scanT[tid] - cnt[tid];
        offsL[tid] = ex;
        curL[tid]  = ex;
        float d = rsqrtf((float)cnt[tid] + 1.0f);
        disL[tid] = d;
        int node = b * 128 + tid;
        if (node < N_NODES) {
            deg[node]  = cnt[tid];
            offs[node] = s + ex;
            dis[node]  = d;
        }
    }
    __syncthreads();
    for (int i = tid; i < m; i += 256) {
        int cl = colL[i];
        int p = atomicAdd(&curL[cl], 1);
        bucketF[s + p] = rowL[i];
    }
    // scale z in place: y = dis * z (node = tid>>1, 16 u32 each)
    int node = tid >> 1, half = tid & 1;
    int gnode = b * 128 + node;
    if (gnode < N_NODES) {
        float d = disL[node];
        unsigned* zp = z32 + (size_t)gnode * 32 + half * 16;
        #pragma unroll
        for (int k = 0; k < 16; ++k) {
            unsigned v = zp[k];
            zp[k] = (unsigned)f2bf(d * bflo(v)) | ((unsigned)f2bf(d * bfhi(v)) << 16);
        }
    }
}

// ---------------- gather_v6 (best measured: 55us): half-wave pairing, clamped loads ---
// Wave handles 8 consecutive nodes. lane = (eo = lane>>5 edge slot, fp = lane&31
// feature pair u32). 8-deep unroll -> 16 edges in flight. y pre-scaled.
__global__ __launch_bounds__(256, 4) void gather_pool_k(const unsigned short* __restrict__ y,
                                                        const int* __restrict__ offs,
                                                        const int* __restrict__ deg,
                                                        const int* __restrict__ bucket,
                                                        const float* __restrict__ dis,
                                                        const int* __restrict__ batch,
                                                        const float* __restrict__ bias,
                                                        float* __restrict__ psum,
                                                        int* __restrict__ pcnt) {
    int lane = threadIdx.x & 63;
    int wid  = threadIdx.x >> 6;
    int i0   = (blockIdx.x * 4 + wid) * 8;   // 100000 = 3125 * 32, exact
    int eo   = lane >> 5;                    // edge slot 0/1
    int fp   = lane & 31;                    // feature pair: feats 2fp, 2fp+1
    float bx = bias[2 * fp], by = bias[2 * fp + 1];
    const unsigned short* yb = y + 2 * fp;

    // prefetch the 8 nodes' metadata lane-parallel, distribute via shfl
    int   om = (lane < 8) ? offs[i0 + lane]  : 0;
    int   dm = (lane < 8) ? deg[i0 + lane]   : 0;
    float sm = (lane < 8) ? dis[i0 + lane]   : 0.f;
    int   gm = (lane < 8) ? batch[i0 + lane] : 0;

    float rx = 0.f, ry = 0.f;
    int cur = -1, runlen = 0;
    #pragma unroll
    for (int n = 0; n < 8; ++n) {
        int i = i0 + n;
        int s = __shfl(om, n);
        int e = s + __shfl(dm, n);

        // self-loop term (pre-scaled y), counted in slot 0 only
        unsigned sv = *(const unsigned*)(yb + (size_t)i * F_OUT);
        float ax = (eo == 0) ? bflo(sv) : 0.f;
        float ay = (eo == 0) ? bfhi(sv) : 0.f;

        for (int j = s; j < e; j += 16) {
            #pragma unroll
            for (int u = 0; u < 8; ++u) {
                int id  = j + 2 * u + eo;
                int idc = (id < e) ? id : e - 1;          // clamp: load unconditional
                int r   = bucket[idc];
                unsigned w = *(const unsigned*)(yb + (size_t)r * F_OUT);
                float wx = bflo(w), wy = bfhi(w);
                ax += (id < e) ? wx : 0.f;                // per-lane cndmask, no branch
                ay += (id < e) ? wy : 0.f;
            }
        }
        // combine the two edge slots (both halves end with the full sum)
        ax += __shfl_xor(ax, 32);
        ay += __shfl_xor(ay, 32);

        float di = __shfl(sm, n);
        float vx = fmaxf(fmaf(di, ax, bx), 0.f);
        float vy = fmaxf(fmaf(di, ay, by), 0.f);
        int g = __shfl(gm, n);
        if (g != cur) {
            if (cur >= 0 && eo == 0) {
                atomicAdd(&psum[cur * F_OUT + 2 * fp],     rx);
                atomicAdd(&psum[cur * F_OUT + 2 * fp + 1], ry);
                if (lane == 0) atomicAdd(&pcnt[cur], runlen);
            }
            cur = g; rx = 0.f; ry = 0.f; runlen = 0;
        }
        rx += vx; ry += vy; runlen++;
    }
    if (cur >= 0 && eo == 0) {
        atomicAdd(&psum[cur * F_OUT + 2 * fp],     rx);
        atomicAdd(&psum[cur * F_OUT + 2 * fp + 1], ry);
        if (lane == 0) atomicAdd(&pcnt[cur], runlen);
    }
}

// ---------------- out = psum / max(count,1) ----------------
__global__ __launch_bounds__(256) void final_k(const float* __restrict__ psum,
                                               const int* __restrict__ pcnt,
                                               float* __restrict__ out) {
    int t = blockIdx.x * blockDim.x + threadIdx.x;
    if (t < N_GRAPHS * F_OUT) {
        int g = t >> 6;
        float c = (float)(pcnt[g] > 1 ? pcnt[g] : 1);
        out[t] = psum[t] / c;
    }
}

extern "C" void kernel_launch(void* const* d_in, const int* in_sizes, int n_in,
                              void* d_out, int out_size, void* d_ws, size_t ws_size,
                              hipStream_t stream) {
    const float* node_feat = (const float*)d_in[0];
    const int*   edges     = (const int*)d_in[1];   // [2, E] flat: row then col
    const int*   batch     = (const int*)d_in[2];
    const float* W         = (const float*)d_in[3];
    const float* b         = (const float*)d_in[4];

    // workspace carve-up (~25 MB)
    unsigned short* z = (unsigned short*)d_ws;               // N*64 bf16 (scaled in place)
    unsigned* part = (unsigned*)(z + (size_t)N_NODES * F_OUT); // E packed (row|col<<17)
    int*   bucketF = (int*)(part + N_EDGES);                 // E
    int*   H       = bucketF + N_EDGES;                      // M_H
    int*   bsumH   = H + M_H;                                // 256
    int*   deg     = bsumH + 256;                            // N
    int*   offs    = deg + N_NODES;                          // N
    float* dis     = (float*)(offs + N_NODES);               // N
    float* psum    = dis + N_NODES;                          // G*64
    int*   pcnt    = (int*)(psum + N_GRAPHS * F_OUT);        // G

    hipMemsetAsync(psum, 0, ((size_t)N_GRAPHS * F_OUT + N_GRAPHS) * 4, stream);

    const int* row = edges;
    const int* col = edges + N_EDGES;

    hist_k<<<NCHK, 256, 0, stream>>>(col, H);
    scanH1_k<<<MB_H, 1024, 0, stream>>>(H, bsumH);
    scanH2_k<<<1, 256, 0, stream>>>(bsumH);
    scanH3_k<<<MB_H, 1024, 0, stream>>>(H, bsumH);
    scatter_lin_k<<<NCHK + NB_LINB, 256, 0, stream>>>(row, col, H, part,
                                                      node_feat, W, z);
    csr_k<<<NBKT, 256, 0, stream>>>(H, part, bucketF, deg, offs, dis, (unsigned*)z);
    gather_pool_k<<<N_NODES / 32, 256, 0, stream>>>(z, offs, deg, bucketF,
                                                    dis, batch, b, psum, pcnt);
    final_k<<<(N_GRAPHS * F_OUT + 255) / 256, 256, 0, stream>>>(psum, pcnt, (float*)d_out);
}